// Round 8
// baseline (153.005 us; speedup 1.0000x reference)
//
#include <hip/hip_runtime.h>
#include <math.h>

typedef unsigned int uint;
typedef unsigned short ushort;
typedef unsigned char uchar;
typedef unsigned long ulong_;
typedef __attribute__((ext_vector_type(4))) float f32x4;

// Problem constants
#define BB  16384
#define DD  64
#define NT_ 128
#define NZ_ 2048
#define NJ_ 2049   // NZ+1

// workspace layout (float offsets) — all regions disjoint (R6 lesson: wzbp8
// is 131072 BYTES = 32768 floats; verify end offsets, not guesses).
#define BIAS_OFF 0         // fp32 [64]                       -> end 64
#define IL2_OFF  64        // il2[c] = exp(-2 lsz)*log2e [2048] -> end 2112
#define A0_OFF   2112      // a0[c]  = -cc * il2         [2048] -> end 4160
#define NIQ_OFF  4160      // niq[c] = -inv * q          [2048] -> end 6208
#define CZ8A_OFF 6208      // fp8 cz k0 [NZ][32] = 16384 floats -> end 22592
#define CZ8B_OFF 22592     // fp8 cz k1                         -> end 38976
#define WZ8A_OFF 38976     // fp8 WzT k0                        -> end 55360
#define WZ8B_OFF 55360     // fp8 WzT k1                        -> end 71744
#define WZBP_OFF 71744     // fp8 Wz packed [64][64][32] B = 32768 floats -> end 104512
#define PART_OFF 104512    // fp32 partials [4][64][NJ_] = 524544 -> end 629056
// end 629056 floats ~= 2.52 MB

// ---------------- fp8 e4m3 (OCP) conversion helpers ----------------
#if __has_builtin(__builtin_amdgcn_cvt_pk_fp8_f32)
__device__ __forceinline__ uint pk4_fp8(float a, float b, float c, float d) {
  int v = __builtin_amdgcn_cvt_pk_fp8_f32(a, b, 0, false);
  v = __builtin_amdgcn_cvt_pk_fp8_f32(c, d, v, true);
  return (uint)v;
}
__device__ __forceinline__ uchar f8_1(float x) {
  return (uchar)(__builtin_amdgcn_cvt_pk_fp8_f32(x, x, 0, false) & 0xFF);
}
#else
__device__ __forceinline__ uint sw_f8(float x) {
  uint u = __float_as_uint(x);
  uint s = (u >> 24) & 0x80u;
  float ax = __uint_as_float(u & 0x7FFFFFFFu);
  if (!(ax >= 0.015625f)) return s;          // flush tiny / NaN -> signed zero
  if (ax >= 448.f) return s | 0x7Eu;
  uint q = __float_as_uint(ax);
  q += 0x7FFFFu + ((q >> 20) & 1u);          // RNE at mantissa bit 20
  uint e = (q >> 23) - 120u;                 // rebias (127 -> 7)
  return s | ((e & 0xFu) << 3) | ((q >> 20) & 7u);
}
__device__ __forceinline__ uchar f8_1(float x) { return (uchar)sw_f8(x); }
__device__ __forceinline__ uint pk4_fp8(float a, float b, float c, float d) {
  return sw_f8(a) | (sw_f8(b) << 8) | (sw_f8(c) << 16) | (sw_f8(d) << 24);
}
#endif

// ---------------------------------------------------------------------------
// Kernel 1 (stage 1): split-K partial sums of W_t = einsum('dij,i->dj').
// 2304 blocks (9/CU, 32 waves/CU) -> latency-tolerant W read (67 MB, BW-bound,
// near the 10.6us HBM floor). R2 lesson: at 8 waves/CU this same pattern
// collapses to ~330 GB/s; keep the high block count.
__global__ __launch_bounds__(256) void k_wt1(
    const float* __restrict__ t, const float* __restrict__ ct,
    const float* __restrict__ lst, const float* __restrict__ W,
    float* __restrict__ part)   // [4][64][NJ_]
{
  __shared__ float ph[32];
  int tx = threadIdx.x;
  int d  = blockIdx.y;
  int ic = blockIdx.z;
  if (tx < 32) {
    int i = ic * 32 + tx;
    float r = fabsf(t[0] - ct[i]) * __expf(-lst[i]);
    ph[tx] = __expf(-r * r);
  }
  __syncthreads();
  int j = blockIdx.x * 256 + tx;
  if (j >= NJ_) return;
  const float* Wp = W + (size_t)d * NT_ * NJ_ + (size_t)(ic * 32) * NJ_ + j;
  float acc = 0.f;
#pragma unroll
  for (int k = 0; k < 32; ++k) acc += Wp[(size_t)k * NJ_] * ph[k];
  part[((size_t)ic * 64 + d) * NJ_ + j] = acc;
}

// ---------------------------------------------------------------------------
// Kernel 2 (stage 2): 256 blocks x 256 thr, 8 centres/block.
// Emits PLANAR per-centre constants {il2, a0, niq}: the swapped-GEMM1 layout
// in k_fused indexes them along quad*4+i, so planar float4 loads are the
// cheap delivery.
__global__ __launch_bounds__(256) void k_prep2(
    const float* __restrict__ part, const float* __restrict__ cz,
    const float* __restrict__ lsz,
    float* __restrict__ bias,
    float* __restrict__ il2a, float* __restrict__ a0a, float* __restrict__ niqa,
    uchar* __restrict__ cz8a, uchar* __restrict__ cz8b,
    uchar* __restrict__ wz8a, uchar* __restrict__ wz8b,
    uchar* __restrict__ wzbp8)
{
  __shared__ float wt[64][9];   // [d][c_local]
  int tid = threadIdx.x;
  int cb0 = blockIdx.x * 8;
#pragma unroll
  for (int h = 0; h < 2; ++h) {
    int f = h * 256 + tid;      // 512 = 64 d x 8 c
    int d = f >> 3, c = f & 7;
    size_t idx = (size_t)d * NJ_ + cb0 + c;
    float s = part[idx] + part[(size_t)64 * NJ_ + idx]
            + part[(size_t)128 * NJ_ + idx] + part[(size_t)192 * NJ_ + idx];
    wt[d][c] = s;
    int cg = cb0 + c;
    wzbp8[((size_t)(cg >> 5) * 64 + d) * 32 + (cg & 31)] = f8_1(s);
  }
  if (blockIdx.x == 0 && tid < 64) {
    size_t idx = (size_t)tid * NJ_ + 2048;
    bias[tid] = part[idx] + part[(size_t)64 * NJ_ + idx]
              + part[(size_t)128 * NJ_ + idx] + part[(size_t)192 * NJ_ + idx];
  }
  __syncthreads();
  int cl = tid >> 5;            // centre within block 0..7
  int k  = tid & 31;            // 0..31
  int c  = cb0 + cl;
  float cv0 = cz[(size_t)c * DD + k];
  float cv1 = cz[(size_t)c * DD + 32 + k];
  cz8a[(size_t)c * 32 + k] = f8_1(cv0);
  cz8b[(size_t)c * 32 + k] = f8_1(cv1);
  float w0 = wt[k][cl], w1 = wt[32 + k][cl];
  wz8a[(size_t)c * 32 + k] = f8_1(w0);
  wz8b[(size_t)c * 32 + k] = f8_1(w1);
  float ca = cv0 * cv0 + cv1 * cv1;
  float qa = w0 * cv0 + w1 * cv1;
  qa += __shfl_xor(qa, 1);  ca += __shfl_xor(ca, 1);
  qa += __shfl_xor(qa, 2);  ca += __shfl_xor(ca, 2);
  qa += __shfl_xor(qa, 4);  ca += __shfl_xor(ca, 4);
  qa += __shfl_xor(qa, 8);  ca += __shfl_xor(ca, 8);
  qa += __shfl_xor(qa, 16); ca += __shfl_xor(ca, 16);
  if (k == 0) {
    float inv = __expf(-2.f * lsz[c]);
    float il2 = inv * 1.44269504f;     // inv * log2e
    il2a[c] = il2;
    a0a[c]  = -ca * il2;               // -cc * il2
    niqa[c] = -inv * qa;               // -inv * q
  }
}

// ---------------------------------------------------------------------------
// Main fused MFMA kernel — R8: occupancy push.
// BM=16, grid 1024. Per-wave state slimmed for VGPR <= 128 so 4 blocks/CU
// (16 waves/CU, 4 waves/SIMD) can be resident — R7 ran 2 waves/SIMD and the
// serial chunk chain (loads->GEMM1->elementwise->transpose->GEMM2) left the
// SIMD ~70% idle (27us wall vs ~4us of issue work).
// Slimming vs R7: single-buffered B-frags (-40 VGPR; exposed L2 latency per
// chunk is what the extra TLP hides), mt dimension dropped, #pragma unroll 1.
// Plain __launch_bounds__(256): R4 lesson — forcing min-waves on a working
// set that doesn't fit makes the backend spill to scratch (11MB, 2x slower);
// let the allocator land where the set is (~115) and occupancy follows.
// Swapped-operand GEMM1 + in-register shuffle transpose (R7): thread owns its
// z-row; phi -> GEMM2-A-frag is 4 shfl + 2 select, no phi LDS buffer.
__global__ __launch_bounds__(256) void k_fused(
    const float* __restrict__ z,
    const uchar* __restrict__ cz8a, const uchar* __restrict__ cz8b,
    const uchar* __restrict__ wz8a, const uchar* __restrict__ wz8b,
    const uchar* __restrict__ wzbp8,
    const float* __restrict__ il2a, const float* __restrict__ a0a,
    const float* __restrict__ niqa,
    const float* __restrict__ bias, float* __restrict__ out)
{
  __shared__ float eps[16 * 68];   // dz combine scratch
  __shared__ float dlr[4][16];

  int tid  = threadIdx.x;
  int ws   = tid >> 6;           // wave = c-split group 0..3
  int lane = tid & 63;
  int lrow = lane & 15, quad = lane >> 4;
  int b0 = blockIdx.x * 16;

  // ---- prologue: read fp32 z row, pack fp8 frags + own-row norm ----
  long az[2];
  float nzz;
  {
    const float* zr = z + (size_t)(b0 + lrow) * DD + quad * 8;
    float4 v0 = *(const float4*)zr;
    float4 v1 = *(const float4*)(zr + 4);
    float4 v2 = *(const float4*)(zr + 32);
    float4 v3 = *(const float4*)(zr + 36);
    uint l0 = pk4_fp8(v0.x, v0.y, v0.z, v0.w);
    uint l1 = pk4_fp8(v1.x, v1.y, v1.z, v1.w);
    uint h0 = pk4_fp8(v2.x, v2.y, v2.z, v2.w);
    uint h1 = pk4_fp8(v3.x, v3.y, v3.z, v3.w);
    az[0] = (long)(((ulong_)l1 << 32) | l0);
    az[1] = (long)(((ulong_)h1 << 32) | h0);
    float ss = v0.x * v0.x + v0.y * v0.y + v0.z * v0.z + v0.w * v0.w
             + v1.x * v1.x + v1.y * v1.y + v1.z * v1.z + v1.w * v1.w
             + v2.x * v2.x + v2.y * v2.y + v2.z * v2.z + v2.w * v2.w
             + v3.x * v3.x + v3.y * v3.y + v3.z * v3.z + v3.w * v3.w;
    ss += __shfl_xor(ss, 16);    // combine the 4 quad partials -> full row sum
    ss += __shfl_xor(ss, 32);
    nzz = -ss;                   // own row's -|z|^2
  }

  f32x4 acc[4];
#pragma unroll
  for (int nt = 0; nt < 4; ++nt) acc[nt] = (f32x4){0.f, 0.f, 0.f, 0.f};
  float dl = 0.f;

  const f32x4 zero = (f32x4){0.f, 0.f, 0.f, 0.f};
  int cbase = ws * 512;

#pragma unroll 1
  for (int it = 0; it < 16; ++it) {
    int c0 = cbase + it * 32;

    // ---- single-buffered loads for this chunk (TLP hides the latency) ----
    long Abc0[2], Abc1[2], Abw0[2], Abw1[2], Abb[4];
    float4 ilv[2], a0v[2], nqv[2];
#pragma unroll
    for (int nt = 0; nt < 2; ++nt) {
      int cg = c0 + nt * 16 + lrow;
      size_t ro = (size_t)cg * 32 + quad * 8;
      Abc0[nt] = *(const long*)(cz8a + ro);
      Abc1[nt] = *(const long*)(cz8b + ro);
      Abw0[nt] = *(const long*)(wz8a + ro);
      Abw1[nt] = *(const long*)(wz8b + ro);
      int cb = c0 + nt * 16 + quad * 4;
      ilv[nt] = *(const float4*)&il2a[cb];
      a0v[nt] = *(const float4*)&a0a[cb];
      nqv[nt] = *(const float4*)&niqa[cb];
    }
    {
      size_t cb_ = (size_t)(c0 >> 5) * 64 * 32;
#pragma unroll
      for (int nt = 0; nt < 4; ++nt)
        Abb[nt] = *(const long*)(wzbp8 + cb_ + (size_t)(nt * 16 + lrow) * 32 + quad * 8);
    }

    // ---- GEMM1 (swapped): thread owns row lrow, c = c0+nt*16+quad*4+i ----
    f32x4 d1a[2], d2a[2];
#pragma unroll
    for (int nt = 0; nt < 2; ++nt) {
      f32x4 d1 = __builtin_amdgcn_mfma_f32_16x16x32_fp8_fp8(Abc0[nt], az[0], zero, 0, 0, 0);
      d1       = __builtin_amdgcn_mfma_f32_16x16x32_fp8_fp8(Abc1[nt], az[1], d1,   0, 0, 0);
      f32x4 d2 = __builtin_amdgcn_mfma_f32_16x16x32_fp8_fp8(Abw0[nt], az[0], zero, 0, 0, 0);
      d2       = __builtin_amdgcn_mfma_f32_16x16x32_fp8_fp8(Abw1[nt], az[1], d2,   0, 0, 0);
      d1a[nt] = d1;
      d2a[nt] = d2;
    }

    // ---- elementwise: p = exp2(clamped), dl accum, pack 4 p's -> uint ----
    uint u0, u1;
#pragma unroll
    for (int nt = 0; nt < 2; ++nt) {
      float pv[4];
#pragma unroll
      for (int i = 0; i < 4; ++i) {
        float il2 = ilv[nt][i];
        float t2  = d1a[nt][i] + d1a[nt][i];
        float uu  = fmaf(il2, nzz, a0v[nt][i]);     // -(zz+cc)*il2
        float e   = fmaf(t2, il2, uu);              // (2 d1 - zz - cc)*il2
        e = fminf(e, 0.f);
        float p;
        asm("v_exp_f32 %0, %1" : "=v"(p) : "v"(e)); // exp2
        float g = fmaf(d2a[nt][i] * 0.69314718f, il2, nqv[nt][i]); // inv*d2 - inv*q
        dl = fmaf(p, g, dl);
        pv[i] = p;
      }
      uint uv = pk4_fp8(pv[0], pv[1], pv[2], pv[3]);
      if (nt == 0) u0 = uv; else u1 = uv;
    }

    // ---- in-wave transpose: phi (own-row layout) -> GEMM2 A-fragment ----
    // target lane (lrow,t) needs phi[row][t*8..t*8+7]; sources are quads
    // 2(t&1), 2(t&1)+1 of tile nt = t>>1.
    int  sl = lrow + ((lane & 16) << 1);   // lrow + 32*(t&1)
    bool hh = lane >= 32;                  // nt = t>>1
    uint l0a = __shfl(u0, sl),      l1a = __shfl(u1, sl);
    uint h0a = __shfl(u0, sl + 16), h1a = __shfl(u1, sl + 16);
    uint lo0 = hh ? l1a : l0a,      hi0 = hh ? h1a : h0a;
    long ap0 = (long)(((ulong_)hi0 << 32) | lo0);

    // ---- GEMM2: dz += phi @ Wz ----
    __builtin_amdgcn_s_setprio(1);
#pragma unroll
    for (int nt = 0; nt < 4; ++nt)
      acc[nt] = __builtin_amdgcn_mfma_f32_16x16x32_fp8_fp8(ap0, Abb[nt], acc[nt], 0, 0, 0);
    __builtin_amdgcn_s_setprio(0);
  }

  // ---- dl partial: sum over the 4 quads holding the same row ----
  {
    float v = dl;
    v += __shfl_xor(v, 16);
    v += __shfl_xor(v, 32);
    if (quad == 0) dlr[ws][lrow] = v;
  }

  // ---- dz combine across the 4 c-split waves ----
  for (int s = 0; s < 4; ++s) {
    __syncthreads();
    if (ws == s) {
#pragma unroll
      for (int nt = 0; nt < 4; ++nt)
#pragma unroll
        for (int i = 0; i < 4; ++i) {
          int r = quad * 4 + i;
          int d = nt * 16 + lrow;
          if (s == 0) eps[r * 68 + d] = acc[nt][i];
          else        eps[r * 68 + d] += acc[nt][i];
        }
    }
  }
  __syncthreads();

  // ---- outputs ----
  {
    int r = tid >> 4, d0 = (tid & 15) * 4;  // 256 thr x 4 floats = 16x64
    float4 e0 = *(const float4*)&eps[r * 68 + d0];
    float4 bv0 = *(const float4*)&bias[d0];
    float4 o0;
    o0.x = e0.x + bv0.x; o0.y = e0.y + bv0.y; o0.z = e0.z + bv0.z; o0.w = e0.w + bv0.w;
    *(float4*)&out[(size_t)(b0 + r) * DD + d0] = o0;
  }
  if (tid < 16) {
    float s = dlr[0][tid] + dlr[1][tid] + dlr[2][tid] + dlr[3][tid];
    out[(size_t)BB * DD + b0 + tid] = 2.f * s;
  }
}

// ---------------------------------------------------------------------------
extern "C" void kernel_launch(void* const* d_in, const int* in_sizes, int n_in,
                              void* d_out, int out_size, void* d_ws, size_t ws_size,
                              hipStream_t stream)
{
  const float* t   = (const float*)d_in[0];
  const float* z   = (const float*)d_in[1];
  // d_in[2] = logp_z (unused)
  const float* cz  = (const float*)d_in[3];
  const float* lsz = (const float*)d_in[4];
  const float* ct  = (const float*)d_in[5];
  const float* lst = (const float*)d_in[6];
  const float* W   = (const float*)d_in[7];
  float* out = (float*)d_out;
  float* ws  = (float*)d_ws;

  float*  bias = ws + BIAS_OFF;
  float*  il2a = ws + IL2_OFF;
  float*  a0a  = ws + A0_OFF;
  float*  niqa = ws + NIQ_OFF;
  uchar*  cz8a = (uchar*)(ws + CZ8A_OFF);
  uchar*  cz8b = (uchar*)(ws + CZ8B_OFF);
  uchar*  wz8a = (uchar*)(ws + WZ8A_OFF);
  uchar*  wz8b = (uchar*)(ws + WZ8B_OFF);
  uchar*  wzbp8 = (uchar*)(ws + WZBP_OFF);
  float*  part = ws + PART_OFF;

  k_wt1<<<dim3(9, 64, 4), 256, 0, stream>>>(t, ct, lst, W, part);
  k_prep2<<<dim3(256), 256, 0, stream>>>(part, cz, lsz, bias,
                                         il2a, a0a, niqa,
                                         cz8a, cz8b, wz8a, wz8b, wzbp8);
  k_fused<<<dim3(BB / 16), 256, 0, stream>>>(z, cz8a, cz8b,
                                             wz8a, wz8b, wzbp8,
                                             il2a, a0a, niqa, bias, out);
}